// Round 6
// baseline (541.152 us; speedup 1.0000x reference)
//
#include <hip/hip_runtime.h>

typedef unsigned short u16;
typedef unsigned int   u32;

#define BTOT 32768
#define BPB  8             // batch elems per block; 128 threads = 2 waves
#define XS   20            // xbuf row stride (floats)
#define XBS  260           // xbuf per-b stride (13*20), 16B-aligned, %32=4 -> conflict-free
#define MU_OFF   22151168  // 32768*4*169
#define LV_OFF   28966912  // + 32768*13*16

// out[j] = B[bbase+j] + sum_m in[m] * W[wbase + j*16 + m]; W/B indices wave-uniform -> s_load
__device__ __forceinline__ void mv16f(const float* __restrict__ W, int wbase,
                                      const float* __restrict__ B, int bbase,
                                      const float* in, float* out) {
#pragma unroll
    for (int j = 0; j < 16; j++) {
        float s = B[bbase + j];
#pragma unroll
        for (int m = 0; m < 16; m++) s += in[m] * W[wbase + j*16 + m];
        out[j] = s;
    }
}

// R6 = R5 (rolled ~20KB body, fits L1I) with 2-wave workgroups.
// R5 finding: occupancy pinned at 44% (~14 waves/CU) with VGPR=52 (allows 32)
// and LDS=4.6KB (allows 34 blocks) -> binding constraint is the ~16
// workgroup-slots/CU HW limit at 1 wave/workgroup. 128-thr blocks: 16 slots
// x 2 waves = 32 waves/CU potential. Data sharing stays inside 16-lane
// groups (waves never exchange data); barriers couple only 2 waves, and
// ~16 resident blocks/CU keep SIMDs fed regardless.
// launch_bounds(128,8): cap VGPR at 64 (body needs 52) for 8 waves/SIMD.
__global__ __launch_bounds__(128, 8) void vae_kernel(
    const float* __restrict__ adj,  const float* __restrict__ initw,
    const float* __restrict__ epsp,
    const float* __restrict__ w0,   const float* __restrict__ b0,
    const float* __restrict__ w1,   const float* __restrict__ b1,
    const float* __restrict__ big,  const float* __restrict__ bib,
    const float* __restrict__ bim,  const float* __restrict__ biv,
    const float* __restrict__ bog,  const float* __restrict__ bob,
    const float* __restrict__ bom,  const float* __restrict__ bov,
    const float* __restrict__ fc1w, const float* __restrict__ fc1b,
    const float* __restrict__ fc2w, const float* __restrict__ fc2b,
    const float* __restrict__ decw, const float* __restrict__ decb,
    float* __restrict__ out)
{
    __shared__ float xbuf[BPB * XBS];   // 8320 B

    const int tid = threadIdx.x;
    const int b   = tid >> 4;          // local batch elem 0..7
    const int n   = tid & 15;          // node row; active if n < 13
    const bool act = (n < 13);
    const int nn  = act ? n : 0;
    const size_t gb = (size_t)blockIdx.x * BPB + b;

    float* myrow = xbuf + b * XBS + n * XS;
    const float* brow = xbuf + b * XBS;

    // ---- adj slice -> 52 regs ----
    float A[4][13];
    {
        const float* ap = adj + gb * 676 + nn * 13;
#pragma unroll
        for (int i = 0; i < 4; i++)
#pragma unroll
            for (int m = 0; m < 13; m++)
                A[i][m] = ap[i*169 + m];
    }

    // ---- init: x = (sum_i adj) @ W ----
    float xr[16];
    {
        float as[13];
#pragma unroll
        for (int m = 0; m < 13; m++) as[m] = A[0][m] + A[1][m] + A[2][m] + A[3][m];
#pragma unroll
        for (int j = 0; j < 16; j++) xr[j] = 0.f;
#pragma unroll
        for (int m = 0; m < 13; m++)
#pragma unroll
            for (int j = 0; j < 16; j++)
                xr[j] += as[m] * initw[m*16 + j];
    }

    if (act) {
        float4* w = (float4*)myrow;
        w[0] = make_float4(xr[0],xr[1],xr[2],xr[3]);
        w[1] = make_float4(xr[4],xr[5],xr[6],xr[7]);
        w[2] = make_float4(xr[8],xr[9],xr[10],xr[11]);
        w[3] = make_float4(xr[12],xr[13],xr[14],xr[15]);
    }
    __syncthreads();

    // ---- 4 GIN layers (ROLLED; all private arrays statically indexed) ----
#pragma unroll 1
    for (int l = 0; l < 4; l++) {
        // BN scalars recomputed in-loop: lane-varying vector loads, L2/L3-cached.
        const int o = l*13 + nn;
        const float si = big[o] * rsqrtf(biv[o] + 1e-5f);
        const float ti = bib[o] - bim[o] * si;
        const float so = bog[o] * rsqrtf(bov[o] + 1e-5f);
        const float to = bob[o] - bom[o] * so;
        const float ep = 1.f + epsp[l];
        const int wb = l << 8;         // l*256
        const int bb = l << 4;         // l*16

        // agg = (1+eps)*x + neighbor   (reads all rows of this b from LDS)
        float acc[16];
#pragma unroll
        for (int j = 0; j < 16; j++) acc[j] = ep * xr[j];
#pragma unroll
        for (int m = 0; m < 13; m++) {
            const float4* rp = (const float4*)(brow + m * XS);
            float4 r0 = rp[0], r1 = rp[1], r2 = rp[2], r3 = rp[3];
            float a0 = A[0][m], a1 = A[1][m], a2 = A[2][m], a3 = A[3][m];
            acc[0]  += a0*r0.x; acc[1]  += a0*r0.y; acc[2]  += a0*r0.z; acc[3]  += a0*r0.w;
            acc[4]  += a1*r1.x; acc[5]  += a1*r1.y; acc[6]  += a1*r1.z; acc[7]  += a1*r1.w;
            acc[8]  += a2*r2.x; acc[9]  += a2*r2.y; acc[10] += a2*r2.z; acc[11] += a2*r2.w;
            acc[12] += a3*r3.x; acc[13] += a3*r3.y; acc[14] += a3*r3.z; acc[15] += a3*r3.w;
        }

        // h1 = leaky(bn_in(agg @ w0^T + b0))
        float h[16];
        mv16f(w0, wb, b0, bb, acc, h);
#pragma unroll
        for (int j = 0; j < 16; j++) {
            float v = si * h[j] + ti;
            h[j] = fmaxf(v, 0.01f * v);
        }
        // x = leaky(bn_out(h @ w1^T + b1))
        mv16f(w1, wb, b1, bb, h, xr);
#pragma unroll
        for (int j = 0; j < 16; j++) {
            float v = so * xr[j] + to;
            xr[j] = fmaxf(v, 0.01f * v);
        }

        __syncthreads();               // all lanes done reading old x
        if (l < 3 && act) {
            float4* w = (float4*)myrow;
            w[0] = make_float4(xr[0],xr[1],xr[2],xr[3]);
            w[1] = make_float4(xr[4],xr[5],xr[6],xr[7]);
            w[2] = make_float4(xr[8],xr[9],xr[10],xr[11]);
            w[3] = make_float4(xr[12],xr[13],xr[14],xr[15]);
        }
        __syncthreads();               // new x visible
    }

    // ---- mu / logvar (row-local) ----
    float mu[16], lv[16];
    mv16f(fc1w, 0, fc1b, 0, xr, mu);
    mv16f(fc2w, 0, fc2b, 0, xr, lv);
    if (act) {
        float4* mo = (float4*)(out + MU_OFF + gb*208 + n*16);
        mo[0] = make_float4(mu[0],mu[1],mu[2],mu[3]);
        mo[1] = make_float4(mu[4],mu[5],mu[6],mu[7]);
        mo[2] = make_float4(mu[8],mu[9],mu[10],mu[11]);
        mo[3] = make_float4(mu[12],mu[13],mu[14],mu[15]);
        float4* lo = (float4*)(out + LV_OFF + gb*208 + n*16);
        lo[0] = make_float4(lv[0],lv[1],lv[2],lv[3]);
        lo[1] = make_float4(lv[4],lv[5],lv[6],lv[7]);
        lo[2] = make_float4(lv[8],lv[9],lv[10],lv[11]);
        lo[3] = make_float4(lv[12],lv[13],lv[14],lv[15]);
    }

    // ---- decoder: z = mu (ROLLED) ----
#pragma unroll 1
    for (int k = 0; k < 4; k++) {
        float tr[16];
        mv16f(decw, k << 8, decb, k << 4, mu, tr);   // temp row n

        if (act) {
            float4* w = (float4*)myrow;
            w[0] = make_float4(tr[0],tr[1],tr[2],tr[3]);
            w[1] = make_float4(tr[4],tr[5],tr[6],tr[7]);
            w[2] = make_float4(tr[8],tr[9],tr[10],tr[11]);
            w[3] = make_float4(tr[12],tr[13],tr[14],tr[15]);
        }
        __syncthreads();               // temp rows visible

        float r[13];
#pragma unroll
        for (int m = 0; m < 13; m++) {
            const float4* rp = (const float4*)(brow + m * XS);
            float4 r0 = rp[0], r1 = rp[1], r2 = rp[2], r3 = rp[3];
            r[m] = tr[0]*r0.x + tr[1]*r0.y + tr[2]*r0.z + tr[3]*r0.w
                 + tr[4]*r1.x + tr[5]*r1.y + tr[6]*r1.z + tr[7]*r1.w
                 + tr[8]*r2.x + tr[9]*r2.y + tr[10]*r2.z + tr[11]*r2.w
                 + tr[12]*r3.x + tr[13]*r3.y + tr[14]*r3.z + tr[15]*r3.w;
        }
        if (act) {
            float* ro = out + gb*676 + (size_t)k*169 + n*13;
#pragma unroll
            for (int m = 0; m < 13; m++) ro[m] = fmaxf(r[m], 0.f);
        }
        __syncthreads();               // readers done before next k overwrites
    }
}

extern "C" void kernel_launch(void* const* d_in, const int* in_sizes, int n_in,
                              void* d_out, int out_size, void* d_ws, size_t ws_size,
                              hipStream_t stream) {
    vae_kernel<<<dim3(BTOT/BPB), dim3(128), 0, stream>>>(
        (const float*)d_in[0],  (const float*)d_in[1],  (const float*)d_in[2],
        (const float*)d_in[3],  (const float*)d_in[4],  (const float*)d_in[5],
        (const float*)d_in[6],  (const float*)d_in[7],  (const float*)d_in[8],
        (const float*)d_in[9],  (const float*)d_in[10], (const float*)d_in[11],
        (const float*)d_in[12], (const float*)d_in[13], (const float*)d_in[14],
        (const float*)d_in[15], (const float*)d_in[16], (const float*)d_in[17],
        (const float*)d_in[18], (const float*)d_in[19], (const float*)d_in[20],
        (float*)d_out);
}

// Round 7
// 365.585 us; speedup vs baseline: 1.4802x; 1.4802x over previous
//
#include <hip/hip_runtime.h>

typedef unsigned short u16;
typedef unsigned int   u32;

#define BTOT 32768
#define BPB  8             // batch elems per block; 128 threads = 2 waves
#define XS   20            // xbuf row stride (floats)
#define XBS  260           // xbuf per-b stride (13*20), 16B-aligned, %32=4 -> conflict-free
#define MU_OFF   22151168  // 32768*4*169
#define LV_OFF   28966912  // + 32768*13*16

// out[j] = B[bbase+j] + sum_m in[m] * W[wbase + j*16 + m]; W/B indices wave-uniform -> s_load
__device__ __forceinline__ void mv16f(const float* __restrict__ W, int wbase,
                                      const float* __restrict__ B, int bbase,
                                      const float* in, float* out) {
#pragma unroll
    for (int j = 0; j < 16; j++) {
        float s = B[bbase + j];
#pragma unroll
        for (int m = 0; m < 16; m++) s += in[m] * W[wbase + j*16 + m];
        out[j] = s;
    }
}

// R7 = R6 (2-wave workgroups to beat the 16-slot/CU occupancy ceiling seen in
// R5) with launch_bounds relaxed (128,8)->(128,4). R6 failure: the (.,8) bound
// drove the allocator to VGPR=32, evicting A[4][13] -> adj rematerialized from
// global every layer (FETCH 45->330 MB, VALUBusy inflated by re-issued loads,
// dur 172->372). The body genuinely needs ~52 VGPR (R5); cap 128 lets regalloc
// keep A resident while 52-64 VGPR still HW-permits 8 waves/SIMD. Slot math:
// 16 workgroups/CU x 2 waves = 32 waves/CU potential (R5's 1-wave groups
// capped at 16 slots -> 44% occ).
__global__ __launch_bounds__(128, 4) void vae_kernel(
    const float* __restrict__ adj,  const float* __restrict__ initw,
    const float* __restrict__ epsp,
    const float* __restrict__ w0,   const float* __restrict__ b0,
    const float* __restrict__ w1,   const float* __restrict__ b1,
    const float* __restrict__ big,  const float* __restrict__ bib,
    const float* __restrict__ bim,  const float* __restrict__ biv,
    const float* __restrict__ bog,  const float* __restrict__ bob,
    const float* __restrict__ bom,  const float* __restrict__ bov,
    const float* __restrict__ fc1w, const float* __restrict__ fc1b,
    const float* __restrict__ fc2w, const float* __restrict__ fc2b,
    const float* __restrict__ decw, const float* __restrict__ decb,
    float* __restrict__ out)
{
    __shared__ float xbuf[BPB * XBS];   // 8320 B

    const int tid = threadIdx.x;
    const int b   = tid >> 4;          // local batch elem 0..7
    const int n   = tid & 15;          // node row; active if n < 13
    const bool act = (n < 13);
    const int nn  = act ? n : 0;
    const size_t gb = (size_t)blockIdx.x * BPB + b;

    float* myrow = xbuf + b * XBS + n * XS;
    const float* brow = xbuf + b * XBS;

    // ---- adj slice -> 52 regs ----
    float A[4][13];
    {
        const float* ap = adj + gb * 676 + nn * 13;
#pragma unroll
        for (int i = 0; i < 4; i++)
#pragma unroll
            for (int m = 0; m < 13; m++)
                A[i][m] = ap[i*169 + m];
    }

    // ---- init: x = (sum_i adj) @ W ----
    float xr[16];
    {
        float as[13];
#pragma unroll
        for (int m = 0; m < 13; m++) as[m] = A[0][m] + A[1][m] + A[2][m] + A[3][m];
#pragma unroll
        for (int j = 0; j < 16; j++) xr[j] = 0.f;
#pragma unroll
        for (int m = 0; m < 13; m++)
#pragma unroll
            for (int j = 0; j < 16; j++)
                xr[j] += as[m] * initw[m*16 + j];
    }

    if (act) {
        float4* w = (float4*)myrow;
        w[0] = make_float4(xr[0],xr[1],xr[2],xr[3]);
        w[1] = make_float4(xr[4],xr[5],xr[6],xr[7]);
        w[2] = make_float4(xr[8],xr[9],xr[10],xr[11]);
        w[3] = make_float4(xr[12],xr[13],xr[14],xr[15]);
    }
    __syncthreads();

    // ---- 4 GIN layers (ROLLED; all private arrays statically indexed) ----
#pragma unroll 1
    for (int l = 0; l < 4; l++) {
        // BN scalars recomputed in-loop: lane-varying vector loads, L2/L3-cached.
        const int o = l*13 + nn;
        const float si = big[o] * rsqrtf(biv[o] + 1e-5f);
        const float ti = bib[o] - bim[o] * si;
        const float so = bog[o] * rsqrtf(bov[o] + 1e-5f);
        const float to = bob[o] - bom[o] * so;
        const float ep = 1.f + epsp[l];
        const int wb = l << 8;         // l*256
        const int bb = l << 4;         // l*16

        // agg = (1+eps)*x + neighbor   (reads all rows of this b from LDS)
        float acc[16];
#pragma unroll
        for (int j = 0; j < 16; j++) acc[j] = ep * xr[j];
#pragma unroll
        for (int m = 0; m < 13; m++) {
            const float4* rp = (const float4*)(brow + m * XS);
            float4 r0 = rp[0], r1 = rp[1], r2 = rp[2], r3 = rp[3];
            float a0 = A[0][m], a1 = A[1][m], a2 = A[2][m], a3 = A[3][m];
            acc[0]  += a0*r0.x; acc[1]  += a0*r0.y; acc[2]  += a0*r0.z; acc[3]  += a0*r0.w;
            acc[4]  += a1*r1.x; acc[5]  += a1*r1.y; acc[6]  += a1*r1.z; acc[7]  += a1*r1.w;
            acc[8]  += a2*r2.x; acc[9]  += a2*r2.y; acc[10] += a2*r2.z; acc[11] += a2*r2.w;
            acc[12] += a3*r3.x; acc[13] += a3*r3.y; acc[14] += a3*r3.z; acc[15] += a3*r3.w;
        }

        // h1 = leaky(bn_in(agg @ w0^T + b0))
        float h[16];
        mv16f(w0, wb, b0, bb, acc, h);
#pragma unroll
        for (int j = 0; j < 16; j++) {
            float v = si * h[j] + ti;
            h[j] = fmaxf(v, 0.01f * v);
        }
        // x = leaky(bn_out(h @ w1^T + b1))
        mv16f(w1, wb, b1, bb, h, xr);
#pragma unroll
        for (int j = 0; j < 16; j++) {
            float v = so * xr[j] + to;
            xr[j] = fmaxf(v, 0.01f * v);
        }

        __syncthreads();               // all lanes done reading old x
        if (l < 3 && act) {
            float4* w = (float4*)myrow;
            w[0] = make_float4(xr[0],xr[1],xr[2],xr[3]);
            w[1] = make_float4(xr[4],xr[5],xr[6],xr[7]);
            w[2] = make_float4(xr[8],xr[9],xr[10],xr[11]);
            w[3] = make_float4(xr[12],xr[13],xr[14],xr[15]);
        }
        __syncthreads();               // new x visible
    }

    // ---- mu / logvar (row-local) ----
    float mu[16], lv[16];
    mv16f(fc1w, 0, fc1b, 0, xr, mu);
    mv16f(fc2w, 0, fc2b, 0, xr, lv);
    if (act) {
        float4* mo = (float4*)(out + MU_OFF + gb*208 + n*16);
        mo[0] = make_float4(mu[0],mu[1],mu[2],mu[3]);
        mo[1] = make_float4(mu[4],mu[5],mu[6],mu[7]);
        mo[2] = make_float4(mu[8],mu[9],mu[10],mu[11]);
        mo[3] = make_float4(mu[12],mu[13],mu[14],mu[15]);
        float4* lo = (float4*)(out + LV_OFF + gb*208 + n*16);
        lo[0] = make_float4(lv[0],lv[1],lv[2],lv[3]);
        lo[1] = make_float4(lv[4],lv[5],lv[6],lv[7]);
        lo[2] = make_float4(lv[8],lv[9],lv[10],lv[11]);
        lo[3] = make_float4(lv[12],lv[13],lv[14],lv[15]);
    }

    // ---- decoder: z = mu (ROLLED) ----
#pragma unroll 1
    for (int k = 0; k < 4; k++) {
        float tr[16];
        mv16f(decw, k << 8, decb, k << 4, mu, tr);   // temp row n

        if (act) {
            float4* w = (float4*)myrow;
            w[0] = make_float4(tr[0],tr[1],tr[2],tr[3]);
            w[1] = make_float4(tr[4],tr[5],tr[6],tr[7]);
            w[2] = make_float4(tr[8],tr[9],tr[10],tr[11]);
            w[3] = make_float4(tr[12],tr[13],tr[14],tr[15]);
        }
        __syncthreads();               // temp rows visible

        float r[13];
#pragma unroll
        for (int m = 0; m < 13; m++) {
            const float4* rp = (const float4*)(brow + m * XS);
            float4 r0 = rp[0], r1 = rp[1], r2 = rp[2], r3 = rp[3];
            r[m] = tr[0]*r0.x + tr[1]*r0.y + tr[2]*r0.z + tr[3]*r0.w
                 + tr[4]*r1.x + tr[5]*r1.y + tr[6]*r1.z + tr[7]*r1.w
                 + tr[8]*r2.x + tr[9]*r2.y + tr[10]*r2.z + tr[11]*r2.w
                 + tr[12]*r3.x + tr[13]*r3.y + tr[14]*r3.z + tr[15]*r3.w;
        }
        if (act) {
            float* ro = out + gb*676 + (size_t)k*169 + n*13;
#pragma unroll
            for (int m = 0; m < 13; m++) ro[m] = fmaxf(r[m], 0.f);
        }
        __syncthreads();               // readers done before next k overwrites
    }
}

extern "C" void kernel_launch(void* const* d_in, const int* in_sizes, int n_in,
                              void* d_out, int out_size, void* d_ws, size_t ws_size,
                              hipStream_t stream) {
    vae_kernel<<<dim3(BTOT/BPB), dim3(128), 0, stream>>>(
        (const float*)d_in[0],  (const float*)d_in[1],  (const float*)d_in[2],
        (const float*)d_in[3],  (const float*)d_in[4],  (const float*)d_in[5],
        (const float*)d_in[6],  (const float*)d_in[7],  (const float*)d_in[8],
        (const float*)d_in[9],  (const float*)d_in[10], (const float*)d_in[11],
        (const float*)d_in[12], (const float*)d_in[13], (const float*)d_in[14],
        (const float*)d_in[15], (const float*)d_in[16], (const float*)d_in[17],
        (const float*)d_in[18], (const float*)d_in[19], (const float*)d_in[20],
        (float*)d_out);
}

// Round 8
// 365.492 us; speedup vs baseline: 1.4806x; 1.0003x over previous
//
#include <hip/hip_runtime.h>

typedef float f32x2 __attribute__((ext_vector_type(2)));
typedef float f32x4 __attribute__((ext_vector_type(4)));

#define BTOT 32768
#define BPB  4             // batch elems per block; 64 threads = ONE wave
#define XS   20            // xbuf row stride (floats)
#define XBS  260           // xbuf per-b stride (13*20), 16B-aligned, %32=4 -> conflict-free
#define MU_OFF   22151168  // 32768*4*169
#define LV_OFF   28966912  // + 32768*13*16

#define LOV(q) __builtin_shufflevector(q, q, 0, 1)
#define HIV(q) __builtin_shufflevector(q, q, 2, 3)

__device__ __forceinline__ f32x2 splat(float s) { f32x2 v; v.x = s; v.y = s; return v; }

// Packed mv: out2[p]=(j=2p,2p+1); out[j] = B[bbase+j] + sum_m in[m]*W[wbase+j*16+m].
// Pairs along m: in2[mp]=(in[2mp],in[2mp+1]), W2[j*8+mp] contiguous -> v_pk_fma_f32
// with zero pair-building cost. Even/odd partial sums combined at the end
// (FP reassociation only).
__device__ __forceinline__ void mv16p(const float* __restrict__ W, int wbase,
                                      const float* __restrict__ B, int bbase,
                                      const f32x2* in2, f32x2* out2) {
    const f32x2* W2 = (const f32x2*)(W + wbase);   // wbase always even
#pragma unroll
    for (int p = 0; p < 8; p++) {
        const int j0 = 2*p, j1 = 2*p + 1;
        f32x2 d0 = in2[0] * W2[j0*8];
        f32x2 d1 = in2[0] * W2[j1*8];
#pragma unroll
        for (int mp = 1; mp < 8; mp++) {
            d0 = __builtin_elementwise_fma(in2[mp], W2[j0*8 + mp], d0);
            d1 = __builtin_elementwise_fma(in2[mp], W2[j1*8 + mp], d1);
        }
        f32x2 o;
        o.x = B[bbase + j0] + d0.x + d0.y;
        o.y = B[bbase + j1] + d1.x + d1.y;
        out2[p] = o;
    }
}

// R8 = R5 (best: 172us rocprof; 1-wave WGs, rolled ~20KB body) + packed-f32
// math. R7 proved TLP is exhausted (2-wave WGs: occ 34%, dur 209; R5 1-wave:
// occ 44%, dur 172; slot-capped). R5 sits ~2.2x above its VALU issue floor
// (~59us); FMA count is the remaining addressable term. f32x2 +
// __builtin_elementwise_fma lowers to v_pk_fma_f32 (2 FMA/instr) on CDNA;
// fallback is 2 scalar FMAs = parity, so regression risk is bounded.
__global__ __launch_bounds__(64, 3) void vae_kernel(
    const float* __restrict__ adj,  const float* __restrict__ initw,
    const float* __restrict__ epsp,
    const float* __restrict__ w0,   const float* __restrict__ b0,
    const float* __restrict__ w1,   const float* __restrict__ b1,
    const float* __restrict__ big,  const float* __restrict__ bib,
    const float* __restrict__ bim,  const float* __restrict__ biv,
    const float* __restrict__ bog,  const float* __restrict__ bob,
    const float* __restrict__ bom,  const float* __restrict__ bov,
    const float* __restrict__ fc1w, const float* __restrict__ fc1b,
    const float* __restrict__ fc2w, const float* __restrict__ fc2b,
    const float* __restrict__ decw, const float* __restrict__ decb,
    float* __restrict__ out)
{
    __shared__ float xbuf[BPB * XBS];   // 4160 B

    const int tid = threadIdx.x;
    const int b   = tid >> 4;          // local batch elem 0..3
    const int n   = tid & 15;          // node row; active if n < 13
    const bool act = (n < 13);
    const int nn  = act ? n : 0;
    const size_t gb = (size_t)blockIdx.x * BPB + b;

    float* myrow = xbuf + b * XBS + n * XS;
    const float* brow = xbuf + b * XBS;

    // ---- adj slice -> 52 regs ----
    float A[4][13];
    {
        const float* ap = adj + gb * 676 + nn * 13;
#pragma unroll
        for (int i = 0; i < 4; i++)
#pragma unroll
            for (int m = 0; m < 13; m++)
                A[i][m] = ap[i*169 + m];
    }

    // ---- init: x = (sum_i adj) @ W  (packed: pairs along j, W j-contiguous) ----
    f32x2 xr2[8];
    {
        float as[13];
#pragma unroll
        for (int m = 0; m < 13; m++) as[m] = A[0][m] + A[1][m] + A[2][m] + A[3][m];
#pragma unroll
        for (int p = 0; p < 8; p++) xr2[p] = splat(0.f);
        const f32x2* iw2 = (const f32x2*)initw;     // iw2[m*8+p] = (W[m][2p],W[m][2p+1])
#pragma unroll
        for (int m = 0; m < 13; m++) {
            const f32x2 am = splat(as[m]);
#pragma unroll
            for (int p = 0; p < 8; p++)
                xr2[p] = __builtin_elementwise_fma(am, iw2[m*8 + p], xr2[p]);
        }
    }

    if (act) {
        f32x4* w = (f32x4*)myrow;
        w[0] = __builtin_shufflevector(xr2[0], xr2[1], 0, 1, 2, 3);
        w[1] = __builtin_shufflevector(xr2[2], xr2[3], 0, 1, 2, 3);
        w[2] = __builtin_shufflevector(xr2[4], xr2[5], 0, 1, 2, 3);
        w[3] = __builtin_shufflevector(xr2[6], xr2[7], 0, 1, 2, 3);
    }
    __syncthreads();                   // single-wave block: ~free

    // ---- 4 GIN layers (ROLLED; all private arrays statically indexed) ----
#pragma unroll 1
    for (int l = 0; l < 4; l++) {
        // BN scalars recomputed in-loop: lane-varying vector loads, L2/L3-cached.
        const int o = l*13 + nn;
        const float si = big[o] * rsqrtf(biv[o] + 1e-5f);
        const float ti = bib[o] - bim[o] * si;
        const float so = bog[o] * rsqrtf(bov[o] + 1e-5f);
        const float to = bob[o] - bom[o] * so;
        const float ep = 1.f + epsp[l];
        const int wb = l << 8;         // l*256
        const int bb = l << 4;         // l*16

        // agg = (1+eps)*x + neighbor (rows from LDS; broadcast addr per b-group)
        f32x2 acc2[8];
        {
            const f32x2 ep2 = splat(ep);
#pragma unroll
            for (int p = 0; p < 8; p++) acc2[p] = ep2 * xr2[p];
        }
#pragma unroll
        for (int m = 0; m < 13; m++) {
            const f32x4* rp = (const f32x4*)(brow + m * XS);
            f32x4 q0 = rp[0], q1 = rp[1], q2 = rp[2], q3 = rp[3];
            const f32x2 a0 = splat(A[0][m]), a1 = splat(A[1][m]);
            const f32x2 a2 = splat(A[2][m]), a3 = splat(A[3][m]);
            acc2[0] = __builtin_elementwise_fma(a0, LOV(q0), acc2[0]);
            acc2[1] = __builtin_elementwise_fma(a0, HIV(q0), acc2[1]);
            acc2[2] = __builtin_elementwise_fma(a1, LOV(q1), acc2[2]);
            acc2[3] = __builtin_elementwise_fma(a1, HIV(q1), acc2[3]);
            acc2[4] = __builtin_elementwise_fma(a2, LOV(q2), acc2[4]);
            acc2[5] = __builtin_elementwise_fma(a2, HIV(q2), acc2[5]);
            acc2[6] = __builtin_elementwise_fma(a3, LOV(q3), acc2[6]);
            acc2[7] = __builtin_elementwise_fma(a3, HIV(q3), acc2[7]);
        }

        // h1 = leaky(bn_in(agg @ w0^T + b0))   (packed)
        f32x2 h2[8];
        mv16p(w0, wb, b0, bb, acc2, h2);
        {
            const f32x2 vsi = splat(si), vti = splat(ti);
#pragma unroll
            for (int p = 0; p < 8; p++) {
                f32x2 v = __builtin_elementwise_fma(vsi, h2[p], vti);
                h2[p] = __builtin_elementwise_max(v, 0.01f * v);
            }
        }
        // x = leaky(bn_out(h @ w1^T + b1))   (packed)
        mv16p(w1, wb, b1, bb, h2, xr2);
        {
            const f32x2 vso = splat(so), vto = splat(to);
#pragma unroll
            for (int p = 0; p < 8; p++) {
                f32x2 v = __builtin_elementwise_fma(vso, xr2[p], vto);
                xr2[p] = __builtin_elementwise_max(v, 0.01f * v);
            }
        }

        __syncthreads();               // all lanes done reading old x
        if (l < 3 && act) {
            f32x4* w = (f32x4*)myrow;
            w[0] = __builtin_shufflevector(xr2[0], xr2[1], 0, 1, 2, 3);
            w[1] = __builtin_shufflevector(xr2[2], xr2[3], 0, 1, 2, 3);
            w[2] = __builtin_shufflevector(xr2[4], xr2[5], 0, 1, 2, 3);
            w[3] = __builtin_shufflevector(xr2[6], xr2[7], 0, 1, 2, 3);
        }
        __syncthreads();               // new x visible
    }

    // ---- mu / logvar (row-local, packed) ----
    f32x2 mu2[8], lv2[8];
    mv16p(fc1w, 0, fc1b, 0, xr2, mu2);
    mv16p(fc2w, 0, fc2b, 0, xr2, lv2);
    if (act) {
        f32x4* mo = (f32x4*)(out + MU_OFF + gb*208 + n*16);
        mo[0] = __builtin_shufflevector(mu2[0], mu2[1], 0, 1, 2, 3);
        mo[1] = __builtin_shufflevector(mu2[2], mu2[3], 0, 1, 2, 3);
        mo[2] = __builtin_shufflevector(mu2[4], mu2[5], 0, 1, 2, 3);
        mo[3] = __builtin_shufflevector(mu2[6], mu2[7], 0, 1, 2, 3);
        f32x4* lo = (f32x4*)(out + LV_OFF + gb*208 + n*16);
        lo[0] = __builtin_shufflevector(lv2[0], lv2[1], 0, 1, 2, 3);
        lo[1] = __builtin_shufflevector(lv2[2], lv2[3], 0, 1, 2, 3);
        lo[2] = __builtin_shufflevector(lv2[4], lv2[5], 0, 1, 2, 3);
        lo[3] = __builtin_shufflevector(lv2[6], lv2[7], 0, 1, 2, 3);
    }

    // ---- decoder: z = mu (ROLLED, packed) ----
#pragma unroll 1
    for (int k = 0; k < 4; k++) {
        f32x2 tr2[8];
        mv16p(decw, k << 8, decb, k << 4, mu2, tr2);   // temp row n

        if (act) {
            f32x4* w = (f32x4*)myrow;
            w[0] = __builtin_shufflevector(tr2[0], tr2[1], 0, 1, 2, 3);
            w[1] = __builtin_shufflevector(tr2[2], tr2[3], 0, 1, 2, 3);
            w[2] = __builtin_shufflevector(tr2[4], tr2[5], 0, 1, 2, 3);
            w[3] = __builtin_shufflevector(tr2[6], tr2[7], 0, 1, 2, 3);
        }
        __syncthreads();               // temp rows visible

        float r[13];
#pragma unroll
        for (int m = 0; m < 13; m++) {
            const f32x4* rp = (const f32x4*)(brow + m * XS);
            f32x4 q0 = rp[0], q1 = rp[1], q2 = rp[2], q3 = rp[3];
            f32x2 d = tr2[0] * LOV(q0);
            d = __builtin_elementwise_fma(tr2[1], HIV(q0), d);
            d = __builtin_elementwise_fma(tr2[2], LOV(q1), d);
            d = __builtin_elementwise_fma(tr2[3], HIV(q1), d);
            d = __builtin_elementwise_fma(tr2[4], LOV(q2), d);
            d = __builtin_elementwise_fma(tr2[5], HIV(q2), d);
            d = __builtin_elementwise_fma(tr2[6], LOV(q3), d);
            d = __builtin_elementwise_fma(tr2[7], HIV(q3), d);
            r[m] = d.x + d.y;
        }
        if (act) {
            float* ro = out + gb*676 + (size_t)k*169 + n*13;
#pragma unroll
            for (int m = 0; m < 13; m++) ro[m] = fmaxf(r[m], 0.f);
        }
        __syncthreads();               // readers done before next k overwrites
    }
}

extern "C" void kernel_launch(void* const* d_in, const int* in_sizes, int n_in,
                              void* d_out, int out_size, void* d_ws, size_t ws_size,
                              hipStream_t stream) {
    vae_kernel<<<dim3(BTOT/BPB), dim3(64), 0, stream>>>(
        (const float*)d_in[0],  (const float*)d_in[1],  (const float*)d_in[2],
        (const float*)d_in[3],  (const float*)d_in[4],  (const float*)d_in[5],
        (const float*)d_in[6],  (const float*)d_in[7],  (const float*)d_in[8],
        (const float*)d_in[9],  (const float*)d_in[10], (const float*)d_in[11],
        (const float*)d_in[12], (const float*)d_in[13], (const float*)d_in[14],
        (const float*)d_in[15], (const float*)d_in[16], (const float*)d_in[17],
        (const float*)d_in[18], (const float*)d_in[19], (const float*)d_in[20],
        (float*)d_out);
}

// Round 9
// 365.099 us; speedup vs baseline: 1.4822x; 1.0011x over previous
//
#include <hip/hip_runtime.h>

typedef float f32x2 __attribute__((ext_vector_type(2)));
typedef float f32x4 __attribute__((ext_vector_type(4)));

#define BTOT 32768
#define BPB  4             // batch elems per block; 64 threads = ONE wave
#define XS   20            // xbuf row stride (floats)
#define XBS  260           // xbuf per-b stride (13*20), 16B-aligned, %32=4 -> conflict-free
#define MU_OFF   22151168  // 32768*4*169
#define LV_OFF   28966912  // + 32768*13*16

#define LOV(q) __builtin_shufflevector(q, q, 0, 1)
#define HIV(q) __builtin_shufflevector(q, q, 2, 3)

__device__ __forceinline__ f32x2 splat(float s) { f32x2 v; v.x = s; v.y = s; return v; }

// 1-wave workgroup "barrier": LDS (DS) operations from the same wavefront
// complete in program order (per-wave DS FIFO), so cross-LANE data through
// LDS needs no s_barrier and no vmcnt/lgkmcnt drain -- only a compile-time
// fence so the compiler doesn't reorder the LDS accesses. Zero instructions.
// (R8 post-mortem: 17 __syncthreads each compiled to s_waitcnt vmcnt(0)
// lgkmcnt(0)+s_barrier, draining in-flight global STORES and weight s_loads
// every layer/k -- the dominant per-wave stall.)
__device__ __forceinline__ void wave_fence() {
    asm volatile("" ::: "memory");
    __builtin_amdgcn_wave_barrier();
}

// Packed mv: out2[p]=(j=2p,2p+1); out[j] = B[bbase+j] + sum_m in[m]*W[wbase+j*16+m].
// Pairs along m -> v_pk_fma_f32, zero pair-building cost.
__device__ __forceinline__ void mv16p(const float* __restrict__ W, int wbase,
                                      const float* __restrict__ B, int bbase,
                                      const f32x2* in2, f32x2* out2) {
    const f32x2* W2 = (const f32x2*)(W + wbase);   // wbase always even
#pragma unroll
    for (int p = 0; p < 8; p++) {
        const int j0 = 2*p, j1 = 2*p + 1;
        f32x2 d0 = in2[0] * W2[j0*8];
        f32x2 d1 = in2[0] * W2[j1*8];
#pragma unroll
        for (int mp = 1; mp < 8; mp++) {
            d0 = __builtin_elementwise_fma(in2[mp], W2[j0*8 + mp], d0);
            d1 = __builtin_elementwise_fma(in2[mp], W2[j1*8 + mp], d1);
        }
        f32x2 o;
        o.x = B[bbase + j0] + d0.x + d0.y;
        o.y = B[bbase + j1] + d1.x + d1.y;
        out2[p] = o;
    }
}

// R9 = R8 (packed math, 1-wave WGs, rolled body) with ALL __syncthreads
// replaced by zero-cost wave fences (see wave_fence comment).
__global__ __launch_bounds__(64, 3) void vae_kernel(
    const float* __restrict__ adj,  const float* __restrict__ initw,
    const float* __restrict__ epsp,
    const float* __restrict__ w0,   const float* __restrict__ b0,
    const float* __restrict__ w1,   const float* __restrict__ b1,
    const float* __restrict__ big,  const float* __restrict__ bib,
    const float* __restrict__ bim,  const float* __restrict__ biv,
    const float* __restrict__ bog,  const float* __restrict__ bob,
    const float* __restrict__ bom,  const float* __restrict__ bov,
    const float* __restrict__ fc1w, const float* __restrict__ fc1b,
    const float* __restrict__ fc2w, const float* __restrict__ fc2b,
    const float* __restrict__ decw, const float* __restrict__ decb,
    float* __restrict__ out)
{
    __shared__ float xbuf[BPB * XBS];   // 4160 B

    const int tid = threadIdx.x;
    const int b   = tid >> 4;          // local batch elem 0..3
    const int n   = tid & 15;          // node row; active if n < 13
    const bool act = (n < 13);
    const int nn  = act ? n : 0;
    const size_t gb = (size_t)blockIdx.x * BPB + b;

    float* myrow = xbuf + b * XBS + n * XS;
    const float* brow = xbuf + b * XBS;

    // ---- adj slice -> 52 regs ----
    float A[4][13];
    {
        const float* ap = adj + gb * 676 + nn * 13;
#pragma unroll
        for (int i = 0; i < 4; i++)
#pragma unroll
            for (int m = 0; m < 13; m++)
                A[i][m] = ap[i*169 + m];
    }

    // ---- init: x = (sum_i adj) @ W  (packed) ----
    f32x2 xr2[8];
    {
        float as[13];
#pragma unroll
        for (int m = 0; m < 13; m++) as[m] = A[0][m] + A[1][m] + A[2][m] + A[3][m];
#pragma unroll
        for (int p = 0; p < 8; p++) xr2[p] = splat(0.f);
        const f32x2* iw2 = (const f32x2*)initw;     // iw2[m*8+p] = (W[m][2p],W[m][2p+1])
#pragma unroll
        for (int m = 0; m < 13; m++) {
            const f32x2 am = splat(as[m]);
#pragma unroll
            for (int p = 0; p < 8; p++)
                xr2[p] = __builtin_elementwise_fma(am, iw2[m*8 + p], xr2[p]);
        }
    }

    if (act) {
        f32x4* w = (f32x4*)myrow;
        w[0] = __builtin_shufflevector(xr2[0], xr2[1], 0, 1, 2, 3);
        w[1] = __builtin_shufflevector(xr2[2], xr2[3], 0, 1, 2, 3);
        w[2] = __builtin_shufflevector(xr2[4], xr2[5], 0, 1, 2, 3);
        w[3] = __builtin_shufflevector(xr2[6], xr2[7], 0, 1, 2, 3);
    }
    wave_fence();                      // ds_write precedes ds_reads in wave order

    // ---- 4 GIN layers (ROLLED; all private arrays statically indexed) ----
#pragma unroll 1
    for (int l = 0; l < 4; l++) {
        // BN scalars recomputed in-loop: lane-varying vector loads, L2/L3-cached.
        const int o = l*13 + nn;
        const float si = big[o] * rsqrtf(biv[o] + 1e-5f);
        const float ti = bib[o] - bim[o] * si;
        const float so = bog[o] * rsqrtf(bov[o] + 1e-5f);
        const float to = bob[o] - bom[o] * so;
        const float ep = 1.f + epsp[l];
        const int wb = l << 8;         // l*256
        const int bb = l << 4;         // l*16

        // agg = (1+eps)*x + neighbor (rows from LDS)
        f32x2 acc2[8];
        {
            const f32x2 ep2 = splat(ep);
#pragma unroll
            for (int p = 0; p < 8; p++) acc2[p] = ep2 * xr2[p];
        }
#pragma unroll
        for (int m = 0; m < 13; m++) {
            const f32x4* rp = (const f32x4*)(brow + m * XS);
            f32x4 q0 = rp[0], q1 = rp[1], q2 = rp[2], q3 = rp[3];
            const f32x2 a0 = splat(A[0][m]), a1 = splat(A[1][m]);
            const f32x2 a2 = splat(A[2][m]), a3 = splat(A[3][m]);
            acc2[0] = __builtin_elementwise_fma(a0, LOV(q0), acc2[0]);
            acc2[1] = __builtin_elementwise_fma(a0, HIV(q0), acc2[1]);
            acc2[2] = __builtin_elementwise_fma(a1, LOV(q1), acc2[2]);
            acc2[3] = __builtin_elementwise_fma(a1, HIV(q1), acc2[3]);
            acc2[4] = __builtin_elementwise_fma(a2, LOV(q2), acc2[4]);
            acc2[5] = __builtin_elementwise_fma(a2, HIV(q2), acc2[5]);
            acc2[6] = __builtin_elementwise_fma(a3, LOV(q3), acc2[6]);
            acc2[7] = __builtin_elementwise_fma(a3, HIV(q3), acc2[7]);
        }

        // h1 = leaky(bn_in(agg @ w0^T + b0))   (packed)
        f32x2 h2[8];
        mv16p(w0, wb, b0, bb, acc2, h2);
        {
            const f32x2 vsi = splat(si), vti = splat(ti);
#pragma unroll
            for (int p = 0; p < 8; p++) {
                f32x2 v = __builtin_elementwise_fma(vsi, h2[p], vti);
                h2[p] = __builtin_elementwise_max(v, 0.01f * v);
            }
        }
        // x = leaky(bn_out(h @ w1^T + b1))   (packed)
        mv16p(w1, wb, b1, bb, h2, xr2);
        {
            const f32x2 vso = splat(so), vto = splat(to);
#pragma unroll
            for (int p = 0; p < 8; p++) {
                f32x2 v = __builtin_elementwise_fma(vso, xr2[p], vto);
                xr2[p] = __builtin_elementwise_max(v, 0.01f * v);
            }
        }

        wave_fence();                  // reads of old x precede overwrite
        if (l < 3 && act) {
            f32x4* w = (f32x4*)myrow;
            w[0] = __builtin_shufflevector(xr2[0], xr2[1], 0, 1, 2, 3);
            w[1] = __builtin_shufflevector(xr2[2], xr2[3], 0, 1, 2, 3);
            w[2] = __builtin_shufflevector(xr2[4], xr2[5], 0, 1, 2, 3);
            w[3] = __builtin_shufflevector(xr2[6], xr2[7], 0, 1, 2, 3);
        }
        wave_fence();                  // new x ordered before next layer's reads
    }

    // ---- mu / logvar (row-local, packed) ----
    f32x2 mu2[8], lv2[8];
    mv16p(fc1w, 0, fc1b, 0, xr2, mu2);
    mv16p(fc2w, 0, fc2b, 0, xr2, lv2);
    if (act) {
        f32x4* mo = (f32x4*)(out + MU_OFF + gb*208 + n*16);
        mo[0] = __builtin_shufflevector(mu2[0], mu2[1], 0, 1, 2, 3);
        mo[1] = __builtin_shufflevector(mu2[2], mu2[3], 0, 1, 2, 3);
        mo[2] = __builtin_shufflevector(mu2[4], mu2[5], 0, 1, 2, 3);
        mo[3] = __builtin_shufflevector(mu2[6], mu2[7], 0, 1, 2, 3);
        f32x4* lo = (f32x4*)(out + LV_OFF + gb*208 + n*16);
        lo[0] = __builtin_shufflevector(lv2[0], lv2[1], 0, 1, 2, 3);
        lo[1] = __builtin_shufflevector(lv2[2], lv2[3], 0, 1, 2, 3);
        lo[2] = __builtin_shufflevector(lv2[4], lv2[5], 0, 1, 2, 3);
        lo[3] = __builtin_shufflevector(lv2[6], lv2[7], 0, 1, 2, 3);
    }
    // no drain: stores retire in background; nothing re-reads these regions.

    // ---- decoder: z = mu (ROLLED, packed) ----
#pragma unroll 1
    for (int k = 0; k < 4; k++) {
        f32x2 tr2[8];
        mv16p(decw, k << 8, decb, k << 4, mu2, tr2);   // temp row n

        if (act) {
            f32x4* w = (f32x4*)myrow;
            w[0] = __builtin_shufflevector(tr2[0], tr2[1], 0, 1, 2, 3);
            w[1] = __builtin_shufflevector(tr2[2], tr2[3], 0, 1, 2, 3);
            w[2] = __builtin_shufflevector(tr2[4], tr2[5], 0, 1, 2, 3);
            w[3] = __builtin_shufflevector(tr2[6], tr2[7], 0, 1, 2, 3);
        }
        wave_fence();                  // temp-row writes ordered before reads

        float r[13];
#pragma unroll
        for (int m = 0; m < 13; m++) {
            const f32x4* rp = (const f32x4*)(brow + m * XS);
            f32x4 q0 = rp[0], q1 = rp[1], q2 = rp[2], q3 = rp[3];
            f32x2 d = tr2[0] * LOV(q0);
            d = __builtin_elementwise_fma(tr2[1], HIV(q0), d);
            d = __builtin_elementwise_fma(tr2[2], LOV(q1), d);
            d = __builtin_elementwise_fma(tr2[3], HIV(q1), d);
            d = __builtin_elementwise_fma(tr2[4], LOV(q2), d);
            d = __builtin_elementwise_fma(tr2[5], HIV(q2), d);
            d = __builtin_elementwise_fma(tr2[6], LOV(q3), d);
            d = __builtin_elementwise_fma(tr2[7], HIV(q3), d);
            r[m] = d.x + d.y;
        }
        if (act) {
            float* ro = out + gb*676 + (size_t)k*169 + n*13;
#pragma unroll
            for (int m = 0; m < 13; m++) ro[m] = fmaxf(r[m], 0.f);
        }
        wave_fence();                  // reads precede next k's overwrite
    }
}

extern "C" void kernel_launch(void* const* d_in, const int* in_sizes, int n_in,
                              void* d_out, int out_size, void* d_ws, size_t ws_size,
                              hipStream_t stream) {
    vae_kernel<<<dim3(BTOT/BPB), dim3(64), 0, stream>>>(
        (const float*)d_in[0],  (const float*)d_in[1],  (const float*)d_in[2],
        (const float*)d_in[3],  (const float*)d_in[4],  (const float*)d_in[5],
        (const float*)d_in[6],  (const float*)d_in[7],  (const float*)d_in[8],
        (const float*)d_in[9],  (const float*)d_in[10], (const float*)d_in[11],
        (const float*)d_in[12], (const float*)d_in[13], (const float*)d_in[14],
        (const float*)d_in[15], (const float*)d_in[16], (const float*)d_in[17],
        (const float*)d_in[18], (const float*)d_in[19], (const float*)d_in[20],
        (float*)d_out);
}